// Round 9
// baseline (154.086 us; speedup 1.0000x reference)
//
#include <hip/hip_runtime.h>
#include <hip/hip_bf16.h>
#include <math.h>

#define P 4096          // number of (even,odd) pairs = B/2
#define DIM 128
#define EPS_F 1e-8f
#define LOG2E 1.4426950408889634f
#define MLG2 1.4426950408889634f   // MARGIN(=1)*log2e, folded into acc init

#define RPB 128         // rows per block (4 waves x 32)
#define CPB 256         // cols per block (4 tiles of 64)
#define TILE_COLS 64
#define NTILES 4
#define NRB (P / RPB)   // 32 row-blocks
#define NCB (P / CPB)   // 16 col-blocks
#define NBLK (NRB * NCB)   // 512 blocks = 2/CU -> co-resident

typedef float f32x4 __attribute__((ext_vector_type(4)));
typedef short bf16x8 __attribute__((ext_vector_type(8)));

static __device__ __forceinline__ void gload_lds16(const void* g, void* l) {
    __builtin_amdgcn_global_load_lds(
        (const __attribute__((address_space(1))) void*)g,
        (__attribute__((address_space(3))) void*)l,
        16, 0, 0);
}

static __device__ __forceinline__ short f2bf(float f) {
    return __builtin_bit_cast(short, __float2bfloat16(f));
}

// Device-scope arrive-and-spin grid barrier. Counter must be 0 at launch
// (memset'd on stream). __threadfence() = agent fence -> L2 writeback /
// invalidate, giving cross-XCD visibility of plain stores.
static __device__ __forceinline__ void gridbar(unsigned int* c) {
    __syncthreads();                 // all block stores issued (vmcnt drained at barrier)
    if (threadIdx.x == 0) {
        __threadfence();             // flush to device coherence point
        __hip_atomic_fetch_add(c, 1u, __ATOMIC_ACQ_REL, __HIP_MEMORY_SCOPE_AGENT);
        while (__hip_atomic_load(c, __ATOMIC_ACQUIRE, __HIP_MEMORY_SCOPE_AGENT) < NBLK)
            __builtin_amdgcn_s_sleep(2);
    }
    __syncthreads();
    __threadfence();                 // acquire side: invalidate stale cache lines
}

__global__ __launch_bounds__(256, 2) void fused(
    const float* __restrict__ x,
    short* __restrict__ xe,      // [P][DIM] bf16 even rows, scaled LOG2E/128
    short* __restrict__ xo,      // [P][DIM] bf16 odd rows
    float* __restrict__ pr,      // [NCB][P] row partials
    float* __restrict__ pc,      // [NRB][P] col partials
    unsigned int* __restrict__ cnt,
    float* __restrict__ out) {

    __shared__ __align__(16) short Bs[2][TILE_COLS * DIM];   // 2 x 16 KB
    __shared__ float wsum[4];

    const int tid = threadIdx.x;
    const int lane = tid & 63;
    const int wave = tid >> 6;

    // ---------------- Phase A: convert + deinterleave (each elem once) ----
    {
        const int base = blockIdx.x * 256 + tid;   // 131072 threads
        #pragma unroll
        for (int h = 0; h < 2; ++h) {
            const int idx = base + h * (NBLK * 256);   // < 262144 float4s
            const int row = idx >> 5;
            const int c4 = idx & 31;
            f32x4 v = *reinterpret_cast<const f32x4*>(x + (size_t)idx * 4);
            const bool odd = row & 1;
            const float s = odd ? 1.0f : (LOG2E / 128.0f);
            short4 pk;
            pk.x = f2bf(v[0] * s); pk.y = f2bf(v[1] * s);
            pk.z = f2bf(v[2] * s); pk.w = f2bf(v[3] * s);
            short* dst = odd ? xo : xe;
            *reinterpret_cast<short4*>(&dst[(size_t)(row >> 1) * DIM + c4 * 4]) = pk;
        }
        if (blockIdx.x == 0 && tid == 0) out[0] = 0.0f;
    }

    gridbar(&cnt[0]);

    // ---------------- Phase B: gram + exp + partial sums ------------------
    {
        const int rb = blockIdx.x >> 4;      // 32 row-blocks
        const int cb = blockIdx.x & 15;      // 16 col-blocks
        const int p0 = rb * RPB;
        const int c0 = cb * CPB;
        const int lrow = lane & 15;
        const int kgrp = (lane >> 4) * 8;    // k offset in shorts

        const char* gB = (const char*)(xo + (size_t)c0 * DIM);
        auto stage = [&](int t) {
            char* lB = (char*)Bs[t & 1];
            const char* gt = gB + (size_t)t * (TILE_COLS * DIM * 2);
            #pragma unroll
            for (int i = 0; i < 4; ++i) {           // 16 KB = 16 x 1 KB chunks
                int Lbase = (wave * 4 + i) * 1024;  // wave-uniform LDS dest
                int L = Lbase + lane * 16;
                int src = L ^ (((L >> 8) & 7) << 4);  // inverse swizzle (involution)
                gload_lds16(gt + src, lB + Lbase);
            }
        };
        stage(0);

        // A fragments (pre-scaled bf16): rows p0 + wave*32 + m*16 + lrow.
        bf16x8 a[2][4];
        #pragma unroll
        for (int m = 0; m < 2; ++m) {
            const short* arow =
                xe + (size_t)(p0 + wave * 32 + m * 16 + lrow) * DIM + kgrp;
            #pragma unroll
            for (int k32 = 0; k32 < 4; ++k32)
                a[m][k32] = *reinterpret_cast<const bf16x8*>(arow + k32 * 32);
        }

        float rs[2][4];        // row partials [m][j]
        float cpp[NTILES][4];  // col partials [t][n] (static idx via unroll)
        #pragma unroll
        for (int m = 0; m < 2; ++m)
            #pragma unroll
            for (int j = 0; j < 4; ++j) rs[m][j] = 0.0f;
        #pragma unroll
        for (int t = 0; t < NTILES; ++t)
            #pragma unroll
            for (int n = 0; n < 4; ++n) cpp[t][n] = 0.0f;

        #pragma unroll
        for (int t = 0; t < NTILES; ++t) {
            __syncthreads();                   // stage(t) landed; buffers safe
            if (t + 1 < NTILES) stage(t + 1);  // in flight across compute(t)

            const short* B = Bs[t & 1];
            f32x4 acc[2][4];
            #pragma unroll
            for (int m = 0; m < 2; ++m)
                #pragma unroll
                for (int n = 0; n < 4; ++n)
                    acc[m][n] = f32x4{MLG2, MLG2, MLG2, MLG2};

            #pragma unroll
            for (int k32 = 0; k32 < 4; ++k32) {
                #pragma unroll
                for (int n = 0; n < 4; ++n) {
                    int cc = n * 16 + lrow;
                    int idx = (cc * DIM + k32 * 32 + kgrp) ^ ((cc & 7) << 3);
                    bf16x8 b = *reinterpret_cast<const bf16x8*>(&B[idx]);
                    #pragma unroll
                    for (int m = 0; m < 2; ++m)
                        acc[m][n] = __builtin_amdgcn_mfma_f32_16x16x32_bf16(
                            a[m][k32], b, acc[m][n], 0, 0, 0);
                }
            }

            // exp2 epilogue (arg = log2e*(1+D)); partials in registers.
            // C/D layout: col = lane&15, row = (lane>>4)*4 + j (m89/m91).
            #pragma unroll
            for (int n = 0; n < 4; ++n)
                #pragma unroll
                for (int m = 0; m < 2; ++m)
                    #pragma unroll
                    for (int j = 0; j < 4; ++j) {
                        float e = exp2f(acc[m][n][j]);
                        rs[m][j] += e;
                        cpp[t][n] += e;
                    }
        }

        // Row sums: reduce across 16 col-lanes of each lane-group; plain store.
        #pragma unroll
        for (int m = 0; m < 2; ++m)
            #pragma unroll
            for (int j = 0; j < 4; ++j) {
                float v = rs[m][j];
                v += __shfl_xor(v, 1);
                v += __shfl_xor(v, 2);
                v += __shfl_xor(v, 4);
                v += __shfl_xor(v, 8);
                rs[m][j] = v;
            }
        if (lrow == 0) {
            int g = lane >> 4;
            #pragma unroll
            for (int m = 0; m < 2; ++m)
                #pragma unroll
                for (int j = 0; j < 4; ++j)
                    pr[(size_t)cb * P + p0 + wave * 32 + m * 16 + g * 4 + j] =
                        rs[m][j];
        }

        // Col sums: shfl over row-groups, cross-wave combine via LDS (reuse Bs).
        __syncthreads();   // all ds_reads of Bs done before reuse
        float* csf = reinterpret_cast<float*>(&Bs[0][0]);   // 4 x 256 floats
        #pragma unroll
        for (int t = 0; t < NTILES; ++t)
            #pragma unroll
            for (int n = 0; n < 4; ++n) {
                float v = cpp[t][n];
                v += __shfl_xor(v, 16);
                v += __shfl_xor(v, 32);
                if (lane < 16)
                    csf[wave * CPB + t * TILE_COLS + n * 16 + lane] = v;
            }
        __syncthreads();
        if (tid < CPB)
            pc[(size_t)rb * P + c0 + tid] = csf[tid] + csf[CPB + tid] +
                                            csf[2 * CPB + tid] + csf[3 * CPB + tid];
    }

    gridbar(&cnt[1]);

    // ---------------- Phase C: gather + corrections + J + loss ------------
    {
        float racc = 0.0f;
        #pragma unroll
        for (int q = 0; q < 2; ++q) {
            const int p = blockIdx.x * 8 + wave * 2 + q;   // [0, P)

            // Partial-sum gather: lanes 0-15 -> pr blocks, 16-47 -> pc blocks.
            float s = 0.0f;
            if (lane < 16)      s = pr[(size_t)lane * P + p];
            else if (lane < 48) s = pc[(size_t)(lane - 16) * P + p];

            const float2* xep = reinterpret_cast<const float2*>(x + (size_t)(2 * p) * DIM);
            const float2* xop = reinterpret_cast<const float2*>(x + (size_t)(2 * p + 1) * DIM);
            float2 ve = xep[lane];
            float2 vo = xop[lane];
            float dpos = ve.x * vo.x + ve.y * vo.y;

            float ci = 0.0f, cj = 0.0f;
            if (p < P / 2) {
                const float2* xi = reinterpret_cast<const float2*>(x + (size_t)(4 * p + 3) * DIM);
                const float2* xj = reinterpret_cast<const float2*>(x + (size_t)(4 * p) * DIM);
                float2 vi = xi[lane];
                float2 vj = xj[lane];
                ci = ve.x * vi.x + ve.y * vi.y;   // dot(x[2p],   x[4p+3])
                cj = vo.x * vj.x + vo.y * vj.y;   // dot(x[2p+1], x[4p])
            }

            #pragma unroll
            for (int off = 32; off > 0; off >>= 1) {
                dpos += __shfl_down(dpos, off);
                ci   += __shfl_down(ci, off);
                cj   += __shfl_down(cj, off);
                s    += __shfl_down(s, off);
            }

            if (lane == 0) {
                float corr = 0.0f;
                if (p < P / 2)
                    corr = __expf(1.0f + ci * (1.0f / 128.0f))
                         + __expf(1.0f + cj * (1.0f / 128.0f));
                float neg = s - corr;
                float J = logf(EPS_F + neg) - dpos * (1.0f / 128.0f);
                float r = fmaxf(J, 0.0f);
                racc += r * r;
            }
        }

        if (lane == 0) wsum[wave] = racc;
        __syncthreads();
        if (tid == 0)
            atomicAdd(out, (wsum[0] + wsum[1] + wsum[2] + wsum[3]) *
                               (1.0f / 8192.0f));
    }
}

extern "C" void kernel_launch(void* const* d_in, const int* in_sizes, int n_in,
                              void* d_out, int out_size, void* d_ws, size_t ws_size,
                              hipStream_t stream) {
    const float* x = (const float*)d_in[0];
    unsigned int* cnt = (unsigned int*)d_ws;            // 2 counters (16 B slot)
    float* pr = (float*)((char*)d_ws + 16);             // NCB * P floats
    float* pc = pr + (size_t)NCB * P;                   // NRB * P floats
    short* xe = (short*)(pc + (size_t)NRB * P);
    short* xo = xe + (size_t)P * DIM;

    hipMemsetAsync(cnt, 0, 8, stream);
    fused<<<NBLK, 256, 0, stream>>>(x, xe, xo, pr, pc, cnt, (float*)d_out);
}

// Round 10
// 31.268 us; speedup vs baseline: 4.9279x; 4.9279x over previous
//
#include <hip/hip_runtime.h>
#include <hip/hip_bf16.h>
#include <math.h>

#define P 4096          // number of (even,odd) pairs = B/2
#define DIM 128
#define EPS_F 1e-8f
#define LOG2E 1.4426950408889634f
#define LN2   0.6931471805599453f
#define MLG2  LOG2E     // MARGIN(=1)*log2e folded into acc init

#define RPB 128         // rows per block (4 waves x 32)
#define CPB 256         // cols per block (4 tiles of 64)
#define TILE_COLS 64
#define NTILES 4
#define NRB (P / RPB)   // 32 row-blocks
#define NCB (P / CPB)   // 16 col-blocks
#define TILE_STRIDE (TILE_COLS * 2 * DIM)   // fp32 elems between B tiles

typedef float f32x4 __attribute__((ext_vector_type(4)));
typedef short bf16x8 __attribute__((ext_vector_type(8)));

static __device__ __forceinline__ short f2bf(float f) {
    return __builtin_bit_cast(short, __float2bfloat16(f));
}

static __device__ __forceinline__ void bload(f32x4* dst, const float* s) {
    #pragma unroll
    for (int u = 0; u < 8; ++u)
        dst[u] = *reinterpret_cast<const f32x4*>(s + u * 4);
}

// Convert 8 staged fp32 regs -> 4 bf16x8 swizzled LDS writes (one B row slice).
static __device__ __forceinline__ void cvtwrite(short* lB, const f32x4* regs,
                                                int br, int bko) {
    #pragma unroll
    for (int u = 0; u < 4; ++u) {
        f32x4 lo = regs[2 * u], hi = regs[2 * u + 1];
        bf16x8 v;
        v[0] = f2bf(lo[0]); v[1] = f2bf(lo[1]);
        v[2] = f2bf(lo[2]); v[3] = f2bf(lo[3]);
        v[4] = f2bf(hi[0]); v[5] = f2bf(hi[1]);
        v[6] = f2bf(hi[2]); v[7] = f2bf(hi[3]);
        int idx = (br * DIM + bko + u * 8) ^ ((br & 7) << 3);
        *reinterpret_cast<bf16x8*>(&lB[idx]) = v;
    }
}

// Single gram kernel, fp32 input direct (no convert pass):
//  M[p,k] = exp2(acc), acc = log2e*(1 + dot(x[2p],x[2k+1])/128)  (bf16 MFMA).
//  pr[cb][p] = per-col-block row sums; pc[rb][k] = per-row-block col sums.
//  Side-channel: dv[p]=acc@(p,p), civ[p]=acc@(p,2p+1), cjv[p]=acc@(2p,p)
//  (pre-exp values; finalize derives D_pos and the two corrections from them).
// B staging: fp32 global->regs issued ONE TILE EARLY, cvt+swizzled ds_write
// next iteration (latency hidden under a full tile of MFMA+exp; no vmcnt
// stall before compute). One barrier per tile.
__global__ __launch_bounds__(256, 2) void gram_fused(
    const float* __restrict__ x,
    float* __restrict__ pr,     // [NCB][P]
    float* __restrict__ pc,     // [NRB][P]
    float* __restrict__ dv,     // [P]
    float* __restrict__ civ,    // [P/2]
    float* __restrict__ cjv,    // [P/2]
    float* __restrict__ out) {

    __shared__ __align__(16) short Bs[2][TILE_COLS * DIM];   // 2 x 16 KB
    __shared__ float csf[4][CPB];                            // 4 KB

    const int tid = threadIdx.x;
    const int lane = tid & 63;
    const int wave = tid >> 6;
    const int cb = blockIdx.x;          // 16 col-blocks
    const int rb = blockIdx.y;          // 32 row-blocks
    const int p0 = rb * RPB;
    const int c0 = cb * CPB;
    const int lrow = lane & 15;
    const int g = lane >> 4;
    const int kgrp = g * 8;

    if (cb == 0 && rb == 0 && tid == 0) out[0] = 0.0f;   // ordered before finalize

    // B staging geometry: thread covers row br (of 64) k-range [bko, bko+32).
    const int br = tid >> 2;
    const int bko = (tid & 3) * 32;
    const float* bbase = x + (size_t)(2 * (c0 + br) + 1) * DIM + bko;

    f32x4 bregA[8], bregB[8];
    bload(bregA, bbase);                       // tile 0
    bload(bregB, bbase + TILE_STRIDE);         // tile 1

    // A fragments: even rows, scale log2e/128 folded into the bf16 convert.
    bf16x8 a[2][4];
    #pragma unroll
    for (int m = 0; m < 2; ++m) {
        const float* arow =
            x + (size_t)(2 * (p0 + wave * 32 + m * 16 + lrow)) * DIM + kgrp;
        #pragma unroll
        for (int k = 0; k < 4; ++k) {
            f32x4 lo = *reinterpret_cast<const f32x4*>(arow + k * 32);
            f32x4 hi = *reinterpret_cast<const f32x4*>(arow + k * 32 + 4);
            bf16x8 r;
            r[0] = f2bf(lo[0] * (LOG2E / 128.f)); r[1] = f2bf(lo[1] * (LOG2E / 128.f));
            r[2] = f2bf(lo[2] * (LOG2E / 128.f)); r[3] = f2bf(lo[3] * (LOG2E / 128.f));
            r[4] = f2bf(hi[0] * (LOG2E / 128.f)); r[5] = f2bf(hi[1] * (LOG2E / 128.f));
            r[6] = f2bf(hi[2] * (LOG2E / 128.f)); r[7] = f2bf(hi[3] * (LOG2E / 128.f));
            a[m][k] = r;
        }
    }

    cvtwrite(Bs[0], bregA, br, bko);   // tile 0 -> LDS (waits its own loads only)

    float rs[2][4];
    float cpp[NTILES][4];
    #pragma unroll
    for (int m = 0; m < 2; ++m)
        #pragma unroll
        for (int j = 0; j < 4; ++j) rs[m][j] = 0.0f;
    #pragma unroll
    for (int t = 0; t < NTILES; ++t)
        #pragma unroll
        for (int n = 0; n < 4; ++n) cpp[t][n] = 0.0f;

    #pragma unroll
    for (int t = 0; t < NTILES; ++t) {
        // Barrier: writes(t) visible to all; compute(t-1) done -> buf (t+1)&1 free.
        __syncthreads();
        if (t + 2 < NTILES)    // issue raw fp32 loads two tiles ahead
            bload(((t & 1) == 0) ? bregA : bregB,
                  bbase + (size_t)(t + 2) * TILE_STRIDE);
        if (t + 1 < NTILES)    // convert + write tile t+1 (loads landed ~1 tile ago)
            cvtwrite(Bs[(t + 1) & 1], ((t & 1) == 0) ? bregB : bregA, br, bko);

        const short* B = Bs[t & 1];
        f32x4 acc[2][4];
        #pragma unroll
        for (int m = 0; m < 2; ++m)
            #pragma unroll
            for (int n = 0; n < 4; ++n)
                acc[m][n] = f32x4{MLG2, MLG2, MLG2, MLG2};

        #pragma unroll
        for (int k32 = 0; k32 < 4; ++k32) {
            #pragma unroll
            for (int n = 0; n < 4; ++n) {
                int cc = n * 16 + lrow;
                int idx = (cc * DIM + k32 * 32 + kgrp) ^ ((cc & 7) << 3);
                bf16x8 b = *reinterpret_cast<const bf16x8*>(&B[idx]);
                #pragma unroll
                for (int m = 0; m < 2; ++m)
                    acc[m][n] = __builtin_amdgcn_mfma_f32_16x16x32_bf16(
                        a[m][k32], b, acc[m][n], 0, 0, 0);
            }
        }

        // Epilogue: exp2, reg partials, side-channel extraction.
        // C/D layout: col = lane&15, row = (lane>>4)*4 + j (m89/m91).
        #pragma unroll
        for (int n = 0; n < 4; ++n) {
            const int C0 = c0 + t * 64 + n * 16;
            const int Cl = C0 + lrow;
            #pragma unroll
            for (int m = 0; m < 2; ++m) {
                const int R0 = p0 + wave * 32 + m * 16;
                const bool pdv = (R0 == C0);                          // uniform
                const bool pci = (C0 + 15 >= 2 * R0 + 1) && (C0 <= 2 * R0 + 31);
                const bool pcj = (R0 + 15 >= 2 * C0) && (R0 <= 2 * C0 + 30);
                #pragma unroll
                for (int j = 0; j < 4; ++j) {
                    float av = acc[m][n][j];
                    float e = exp2f(av);
                    rs[m][j] += e;
                    cpp[t][n] += e;
                    int Rj = R0 + g * 4 + j;
                    if (pdv && Cl == Rj)         dv[Rj] = av;
                    if (pci && Cl == 2 * Rj + 1) civ[Rj] = av;
                    if (pcj && Rj == 2 * Cl)     cjv[Cl] = av;
                }
            }
        }
    }

    // Row sums: reduce across the 16 col-lanes of each lane-group; plain store.
    #pragma unroll
    for (int m = 0; m < 2; ++m)
        #pragma unroll
        for (int j = 0; j < 4; ++j) {
            float v = rs[m][j];
            v += __shfl_xor(v, 1);
            v += __shfl_xor(v, 2);
            v += __shfl_xor(v, 4);
            v += __shfl_xor(v, 8);
            rs[m][j] = v;
        }
    if (lrow == 0) {
        #pragma unroll
        for (int m = 0; m < 2; ++m)
            #pragma unroll
            for (int j = 0; j < 4; ++j)
                pr[(size_t)cb * P + p0 + wave * 32 + m * 16 + g * 4 + j] =
                    rs[m][j];
    }

    // Col sums: shfl over row-groups, cross-wave combine via csf.
    #pragma unroll
    for (int t = 0; t < NTILES; ++t)
        #pragma unroll
        for (int n = 0; n < 4; ++n) {
            float v = cpp[t][n];
            v += __shfl_xor(v, 16);
            v += __shfl_xor(v, 32);
            if (lane < 16)
                csf[wave][t * TILE_COLS + n * 16 + lane] = v;
        }
    __syncthreads();
    if (tid < CPB)
        pc[(size_t)rb * P + c0 + tid] =
            csf[0][tid] + csf[1][tid] + csf[2][tid] + csf[3][tid];
}

// Finalize: tiny — 0.8 MB of partials + side-channel values, no x reads.
__global__ __launch_bounds__(256) void finalize(
    const float* __restrict__ pr,
    const float* __restrict__ pc,
    const float* __restrict__ dv,
    const float* __restrict__ civ,
    const float* __restrict__ cjv,
    float* __restrict__ out) {

    __shared__ float wsum[4];
    const int tid = threadIdx.x;
    const int lane = tid & 63;
    const int wave = tid >> 6;
    const int p = blockIdx.x * 256 + tid;   // grid = 16 -> p in [0,P)

    float s = 0.0f;
    #pragma unroll
    for (int b = 0; b < NCB; ++b) s += pr[(size_t)b * P + p];
    #pragma unroll
    for (int b = 0; b < NRB; ++b) s += pc[(size_t)b * P + p];

    float corr = 0.0f;
    if (p < P / 2) corr = exp2f(civ[p]) + exp2f(cjv[p]);

    float Dpos = dv[p] * LN2 - 1.0f;      // dv = log2e*(1+D)  ->  D
    float J = logf(EPS_F + (s - corr)) - Dpos;
    float r = fmaxf(J, 0.0f);
    r = r * r;

    #pragma unroll
    for (int off = 32; off > 0; off >>= 1) r += __shfl_down(r, off);
    if (lane == 0) wsum[wave] = r;
    __syncthreads();
    if (tid == 0)
        atomicAdd(out, (wsum[0] + wsum[1] + wsum[2] + wsum[3]) *
                           (1.0f / 8192.0f));
}

extern "C" void kernel_launch(void* const* d_in, const int* in_sizes, int n_in,
                              void* d_out, int out_size, void* d_ws, size_t ws_size,
                              hipStream_t stream) {
    const float* x = (const float*)d_in[0];
    float* pr = (float*)d_ws;                     // NCB*P floats
    float* pc = pr + (size_t)NCB * P;             // NRB*P floats
    float* dv = pc + (size_t)NRB * P;             // P
    float* civ = dv + P;                          // P/2
    float* cjv = civ + P / 2;                     // P/2

    dim3 grid(NCB, NRB);   // (16, 32) = 512 blocks
    gram_fused<<<grid, 256, 0, stream>>>(x, pr, pc, dv, civ, cjv, (float*)d_out);
    finalize<<<P / 256, 256, 0, stream>>>(pr, pc, dv, civ, cjv, (float*)d_out);
}